// Round 11
// baseline (214.684 us; speedup 1.0000x reference)
//
#include <hip/hip_runtime.h>
#include <math.h>

#define IN_CH 128
#define H1N 8
#define C1N 16
#define C2N 64
#define NEG_SLOPE 0.2f

#define BKT_SHIFT 7                 // 128 nodes per bucket
#define BKT_NODES (1 << BKT_SHIFT)
#define NBLK 128                    // blocks for count/bin passes

typedef unsigned short ushortT;
typedef unsigned char ucharT;

__device__ __forceinline__ ushortT f2bf(float f) {
    unsigned u = __float_as_uint(f);
    unsigned r = u + 0x7FFFu + ((u >> 16) & 1u);
    return (ushortT)(r >> 16);
}
__device__ __forceinline__ float bf2f(ushortT b) {
    return __uint_as_float(((unsigned)b) << 16);
}
__device__ __forceinline__ float leaky(float x) {
    return (x > 0.f) ? x : NEG_SLOPE * x;
}

// ---------------- CSR build: deterministic counting sort, no global atomics ----------------

__global__ __launch_bounds__(512) void k_cnt(const int* __restrict__ src,
                                             const int* __restrict__ dst,
                                             int E, int N, int* __restrict__ cnt) {
    __shared__ int hist[512];
    int blk = blockIdx.x, t = threadIdx.x;
    int nb = (N + BKT_NODES - 1) >> BKT_SHIFT;
    if (t < nb) hist[t] = 0;
    __syncthreads();
    int Etot = E + N;
    int chunk = (Etot + gridDim.x - 1) / gridDim.x;
    int lo = blk * chunk;
    int hi = lo + chunk; if (hi > Etot) hi = Etot;
    for (int i = lo + t; i < hi; i += 512) {
        int d = (i < E) ? dst[i] : (i - E);
        atomicAdd(&hist[d >> BKT_SHIFT], 1);
    }
    __syncthreads();
    if (t < nb) cnt[t * NBLK + blk] = hist[t];
}

__global__ __launch_bounds__(NBLK) void k_scanrel(int* __restrict__ cnt,
                                                  int* __restrict__ bucketTotal) {
    __shared__ int sh[NBLK];
    int b = blockIdx.x, t = threadIdx.x;
    sh[t] = cnt[b * NBLK + t];
    __syncthreads();
    for (int off = 1; off < NBLK; off <<= 1) {
        int v = (t >= off) ? sh[t - off] : 0;
        __syncthreads();
        sh[t] += v;
        __syncthreads();
    }
    if (t == NBLK - 1) bucketTotal[b] = sh[t];
    cnt[b * NBLK + t] = (t == 0) ? 0 : sh[t - 1];
}

__global__ __launch_bounds__(512) void k_scanbucket(const int* __restrict__ bucketTotal,
                                                    int nb, int* __restrict__ bBase,
                                                    int N, int* __restrict__ offsets) {
    __shared__ int sh[512];
    int t = threadIdx.x;
    sh[t] = (t < nb) ? bucketTotal[t] : 0;
    __syncthreads();
    for (int off = 1; off < 512; off <<= 1) {
        int v = (t >= off) ? sh[t - off] : 0;
        __syncthreads();
        sh[t] += v;
        __syncthreads();
    }
    if (t < nb) bBase[t] = (t == 0) ? 0 : sh[t - 1];
    if (t == 511) { bBase[nb] = sh[511]; offsets[N] = sh[511]; }
}

__global__ __launch_bounds__(512) void k_bin(const int* __restrict__ src,
                                             const int* __restrict__ dst,
                                             int E, int N,
                                             const int* __restrict__ cnt,
                                             const int* __restrict__ bBase,
                                             unsigned* __restrict__ pair) {
    __shared__ int cur[512];
    int blk = blockIdx.x, t = threadIdx.x;
    int nb = (N + BKT_NODES - 1) >> BKT_SHIFT;
    if (t < nb) cur[t] = bBase[t] + cnt[t * NBLK + blk];
    __syncthreads();
    int Etot = E + N;
    int chunk = (Etot + gridDim.x - 1) / gridDim.x;
    int lo = blk * chunk;
    int hi = lo + chunk; if (hi > Etot) hi = Etot;
    for (int i = lo + t; i < hi; i += 512) {
        int s, d;
        if (i < E) { s = src[i]; d = dst[i]; }
        else       { s = d = i - E; }
        int b = d >> BKT_SHIFT;
        int pos = atomicAdd(&cur[b], 1);
        pair[pos] = ((unsigned)(d & (BKT_NODES - 1)) << 16) | (unsigned)s;
    }
}

// one block per bucket: LDS histogram + scan -> offsets, uint16 CSR, uint8 dst-local
__global__ __launch_bounds__(256) void k_csr_local(const unsigned* __restrict__ pair,
                                                   const int* __restrict__ bBase,
                                                   int N, int* __restrict__ offsets,
                                                   ushortT* __restrict__ csr,
                                                   ucharT* __restrict__ dloc) {
    __shared__ int hist[BKT_NODES];
    __shared__ int loff[BKT_NODES];
    int b = blockIdx.x;
    int t = threadIdx.x;
    int base = bBase[b];
    int cnt = bBase[b + 1] - base;
    const unsigned* pp = pair + base;

    if (t < BKT_NODES) hist[t] = 0;
    __syncthreads();
    for (int i = t; i < cnt; i += 256) atomicAdd(&hist[pp[i] >> 16], 1);
    __syncthreads();
    if (t < BKT_NODES) loff[t] = hist[t];
    __syncthreads();
    for (int off = 1; off < BKT_NODES; off <<= 1) {
        int v = 0;
        if (t < BKT_NODES && t >= off) v = loff[t - off];
        __syncthreads();
        if (t < BKT_NODES) loff[t] += v;
        __syncthreads();
    }
    int node0 = b << BKT_SHIFT;
    if (t < BKT_NODES) {
        int excl = (t == 0) ? 0 : loff[t - 1];
        hist[t] = excl;
        int g = node0 + t;
        if (g < N) offsets[g] = base + excl;
    }
    __syncthreads();
    for (int i = t; i < cnt; i += 256) {
        unsigned pk = pp[i];
        int dl = pk >> 16;
        int pos = atomicAdd(&hist[dl], 1);
        csr[base + pos]  = (ushortT)(pk & 0xFFFFu);
        dloc[base + pos] = (ucharT)dl;
    }
}

// ---------------- GEMM + fused attention coefficients ----------------

template <int KOUT, int HEADS>
__global__ __launch_bounds__(256) void k_gemm_att(const float* __restrict__ A,
                                                  const float* __restrict__ W,
                                                  const float* __restrict__ att_s,
                                                  const float* __restrict__ att_d,
                                                  int N, ushortT* __restrict__ Cbf,
                                                  float* __restrict__ as_,
                                                  float* __restrict__ ad_) {
    constexpr int CG  = KOUT / 4;
    constexpr int TY  = 256 / CG;
    constexpr int RPT = 64 / TY;
    constexpr int RW  = (KOUT / HEADS) / 4;
    static_assert(RW == 4 || RW == 16, "reduce width");
    __shared__ float As[64][16];
    __shared__ float Ws[16][KOUT];
    int t = threadIdx.x;
    int row0 = blockIdx.x * 64;
    int tx = t % CG, ty = t / CG;

    float4 acc[RPT];
#pragma unroll
    for (int i = 0; i < RPT; ++i) acc[i] = make_float4(0.f, 0.f, 0.f, 0.f);

    for (int k0 = 0; k0 < IN_CH; k0 += 16) {
        {
            int r  = t >> 2;
            int cc = (t & 3) * 4;
            int gr = row0 + r;
            float4 v = make_float4(0.f, 0.f, 0.f, 0.f);
            if (gr < N) v = *(const float4*)(A + (size_t)gr * IN_CH + k0 + cc);
            *(float4*)(&As[r][cc]) = v;
        }
        {
            constexpr int TOT = 16 * KOUT / 4;
            for (int idx = t; idx < TOT; idx += 256) {
                int rr = idx / (KOUT / 4);
                int cc = (idx % (KOUT / 4)) * 4;
                *(float4*)(&Ws[rr][cc]) = *(const float4*)(W + (size_t)(k0 + rr) * KOUT + cc);
            }
        }
        __syncthreads();
#pragma unroll
        for (int kk = 0; kk < 16; ++kk) {
            float4 w = *(const float4*)(&Ws[kk][tx * 4]);
#pragma unroll
            for (int i = 0; i < RPT; ++i) {
                float a = As[ty * RPT + i][kk];
                acc[i].x += a * w.x; acc[i].y += a * w.y;
                acc[i].z += a * w.z; acc[i].w += a * w.w;
            }
        }
        __syncthreads();
    }

    float4 s4 = *(const float4*)(att_s + tx * 4);
    float4 d4 = *(const float4*)(att_d + tx * 4);
#pragma unroll
    for (int i = 0; i < RPT; ++i) {
        int gr = row0 + ty * RPT + i;
        float as = acc[i].x * s4.x + acc[i].y * s4.y + acc[i].z * s4.z + acc[i].w * s4.w;
        float ad = acc[i].x * d4.x + acc[i].y * d4.y + acc[i].z * d4.z + acc[i].w * d4.w;
#pragma unroll
        for (int o = 1; o < RW; o <<= 1) {
            as += __shfl_xor(as, o);
            ad += __shfl_xor(ad, o);
        }
        if (gr < N) {
            ushort4 pk;
            pk.x = f2bf(acc[i].x); pk.y = f2bf(acc[i].y);
            pk.z = f2bf(acc[i].z); pk.w = f2bf(acc[i].w);
            *(ushort4*)(Cbf + (size_t)gr * KOUT + tx * 4) = pk;
            if ((tx % RW) == 0) {
                int h = tx / RW;
                as_[(size_t)gr * HEADS + h] = as;
                ad_[(size_t)gr * HEADS + h] = ad;
            }
        }
    }
}

// ---------------- edge-parallel softmax-weight precompute ----------------
// one block per bucket; p1T[h][edge] (bf16, csr order). as1 is 1.6MB -> L2-resident.

__global__ __launch_bounds__(256) void k_pexp1(const ushortT* __restrict__ csr,
                                               const ucharT* __restrict__ dloc,
                                               const int* __restrict__ bBase,
                                               const float* __restrict__ as1,
                                               const float* __restrict__ ad1,
                                               int N, int Etot,
                                               ushortT* __restrict__ p1T) {
    __shared__ float ad1s[BKT_NODES * H1N];
    int b = blockIdx.x, t = threadIdx.x;
    int node0 = b << BKT_SHIFT;
    for (int i = t; i < BKT_NODES * H1N; i += 256) {
        int g = node0 + (i >> 3);
        ad1s[i] = (g < N) ? ad1[(size_t)g * H1N + (i & 7)] : 0.f;
    }
    __syncthreads();
    int base = bBase[b];
    int cnt  = bBase[b + 1] - base;
#pragma unroll
    for (int h = 0; h < H1N; ++h) {
        for (int i = t; i < cnt; i += 256) {
            int s  = csr[base + i];
            int dl = dloc[base + i];
            float a = as1[(size_t)s * H1N + h] + ad1s[dl * H1N + h];
            p1T[(size_t)h * Etot + base + i] = f2bf(__expf(leaky(a)));
        }
    }
}

__global__ __launch_bounds__(256) void k_pexp2(const ushortT* __restrict__ csr,
                                               const ucharT* __restrict__ dloc,
                                               const int* __restrict__ bBase,
                                               const float* __restrict__ as2,
                                               const float* __restrict__ ad2,
                                               int N,
                                               ushortT* __restrict__ p2) {
    __shared__ float ad2s[BKT_NODES];
    int b = blockIdx.x, t = threadIdx.x;
    int node0 = b << BKT_SHIFT;
    if (t < BKT_NODES) {
        int g = node0 + t;
        ad2s[t] = (g < N) ? ad2[g] : 0.f;
    }
    __syncthreads();
    int base = bBase[b];
    int cnt  = bBase[b + 1] - base;
    for (int i = t; i < cnt; i += 256) {
        int s  = csr[base + i];
        int dl = dloc[base + i];
        p2[base + i] = f2bf(__expf(leaky(as2[s] + ad2s[dl])));
    }
}

// ---------------- layer 1 aggregation (+bias +ELU) ----------------
// one wave per node; lane owns channels 2*lane,2*lane+1 (head hc=lane>>3).
// Hot loop has NO exp/shfl: p is precomputed; chain = csr load -> h1 gather.

__global__ __launch_bounds__(256) void k_agg1(const ushortT* __restrict__ h1bf,
                       const ushortT* __restrict__ p1T,
                       const int* __restrict__ offsets, const ushortT* __restrict__ csr,
                       const float* __restrict__ b1,
                       int N, int Etot, float* __restrict__ h2in) {
    int wid  = (blockIdx.x * blockDim.x + threadIdx.x) >> 6;
    int lane = threadIdx.x & 63;
    if (wid >= N) return;
    int v = wid;
    int hc = lane >> 3;
    const ushortT* pT = p1T + (size_t)hc * Etot;
    float denom = 0.f, acc0 = 0.f, acc1 = 0.f;
    int beg = offsets[v], end = offsets[v + 1];
    int j = beg;
    for (; j + 8 <= end; j += 8) {
#pragma unroll
        for (int e = 0; e < 8; ++e) {
            int se = csr[j + e];
            float pe = bf2f(pT[j + e]);
            unsigned q = *(const unsigned*)(h1bf + (size_t)se * IN_CH + lane * 2);
            denom += pe;
            acc0 = fmaf(pe, bf2f((ushortT)(q & 0xFFFFu)), acc0);
            acc1 = fmaf(pe, bf2f((ushortT)(q >> 16)), acc1);
        }
    }
    for (; j < end; ++j) {
        int se = csr[j];
        float pe = bf2f(pT[j]);
        unsigned q = *(const unsigned*)(h1bf + (size_t)se * IN_CH + lane * 2);
        denom += pe;
        acc0 = fmaf(pe, bf2f((ushortT)(q & 0xFFFFu)), acc0);
        acc1 = fmaf(pe, bf2f((ushortT)(q >> 16)), acc1);
    }
    float inv = 1.f / (denom + 1e-16f);
    float o0 = acc0 * inv + b1[lane * 2];
    float o1 = acc1 * inv + b1[lane * 2 + 1];
    o0 = (o0 > 0.f) ? o0 : expm1f(o0);
    o1 = (o1 > 0.f) ? o1 : expm1f(o1);
    float2 ov; ov.x = o0; ov.y = o1;
    *(float2*)(h2in + (size_t)v * IN_CH + lane * 2) = ov;
}

// ---------------- layer 2 aggregation (+bias) + log_softmax ----------------

__global__ __launch_bounds__(256) void k_agg2(const ushortT* __restrict__ h2bf,
                       const ushortT* __restrict__ p2,
                       const int* __restrict__ offsets, const ushortT* __restrict__ csr,
                       const float* __restrict__ b2,
                       int N, float* __restrict__ out) {
    int wid  = (blockIdx.x * blockDim.x + threadIdx.x) >> 6;
    int lane = threadIdx.x & 63;
    if (wid >= N) return;
    int v = wid;
    float denom = 0.f, acc = 0.f;
    int beg = offsets[v], end = offsets[v + 1];
    int j = beg;
    for (; j + 8 <= end; j += 8) {
#pragma unroll
        for (int e = 0; e < 8; ++e) {
            int se = csr[j + e];
            float pe = bf2f(p2[j + e]);
            float x = bf2f(h2bf[(size_t)se * C2N + lane]);
            denom += pe;
            acc = fmaf(pe, x, acc);
        }
    }
    for (; j < end; ++j) {
        int se = csr[j];
        float pe = bf2f(p2[j]);
        float x = bf2f(h2bf[(size_t)se * C2N + lane]);
        denom += pe;
        acc = fmaf(pe, x, acc);
    }
    float o = acc / (denom + 1e-16f) + b2[lane];
    float mx = o;
#pragma unroll
    for (int off = 32; off >= 1; off >>= 1) mx = fmaxf(mx, __shfl_xor(mx, off));
    float e = __expf(o - mx);
    float se = e;
#pragma unroll
    for (int off = 32; off >= 1; off >>= 1) se += __shfl_xor(se, off);
    out[(size_t)v * C2N + lane] = o - mx - logf(se);
}

// ---------------- launch ----------------

extern "C" void kernel_launch(void* const* d_in, const int* in_sizes, int n_in,
                              void* d_out, int out_size, void* d_ws, size_t ws_size,
                              hipStream_t stream) {
    const float* x      = (const float*)d_in[0];
    const int*   ei     = (const int*)d_in[1];
    const float* W1     = (const float*)d_in[2];
    const float* att_s1 = (const float*)d_in[3];
    const float* att_d1 = (const float*)d_in[4];
    const float* b1     = (const float*)d_in[5];
    const float* W2     = (const float*)d_in[6];
    const float* att_s2 = (const float*)d_in[7];
    const float* att_d2 = (const float*)d_in[8];
    const float* b2     = (const float*)d_in[9];

    int N = in_sizes[0] / IN_CH;
    int E = in_sizes[1] / 2;
    const int* srcA = ei;
    const int* dstA = ei + E;
    int Etot = E + N;
    int nb = (N + BKT_NODES - 1) >> BKT_SHIFT;

    char* p = (char*)d_ws;
    auto carve = [&](size_t bytes) {
        void* r = (void*)p;
        p += (bytes + 255) & ~(size_t)255;
        return r;
    };
    ushortT* h1bf = (ushortT*)carve((size_t)N * IN_CH * 2);
    ushortT* h2bf = (ushortT*)carve((size_t)N * C2N * 2);
    float* h2in = (float*)carve((size_t)N * IN_CH * 4);
    float* as1  = (float*)carve((size_t)N * H1N * 4);
    float* ad1  = (float*)carve((size_t)N * H1N * 4);
    float* as2  = (float*)carve((size_t)N * 4);
    float* ad2  = (float*)carve((size_t)N * 4);
    int* offsets     = (int*)carve((size_t)(N + 1) * 4);
    ushortT* csr     = (ushortT*)carve((size_t)Etot * 2);
    ucharT* dloc     = (ucharT*)carve((size_t)Etot);
    int* cnt         = (int*)carve((size_t)nb * NBLK * 4);
    int* bucketTotal = (int*)carve((size_t)nb * 4);
    int* bBase       = (int*)carve((size_t)(nb + 1) * 4);
    unsigned* pair   = (unsigned*)carve((size_t)Etot * 4);
    ushortT* p1T     = (ushortT*)carve((size_t)H1N * Etot * 2);
    ushortT* p2      = (ushortT*)carve((size_t)Etot * 2);

    // CSR build (deterministic counting sort; no global atomics)
    k_cnt<<<NBLK, 512, 0, stream>>>(srcA, dstA, E, N, cnt);
    k_scanrel<<<nb, NBLK, 0, stream>>>(cnt, bucketTotal);
    k_scanbucket<<<1, 512, 0, stream>>>(bucketTotal, nb, bBase, N, offsets);
    k_bin<<<NBLK, 512, 0, stream>>>(srcA, dstA, E, N, cnt, bBase, pair);
    k_csr_local<<<nb, 256, 0, stream>>>(pair, bBase, N, offsets, csr, dloc);

    // layer 1
    k_gemm_att<128, 8><<<(N + 63) / 64, 256, 0, stream>>>(x, W1, att_s1, att_d1,
                                                          N, h1bf, as1, ad1);
    k_pexp1<<<nb, 256, 0, stream>>>(csr, dloc, bBase, as1, ad1, N, Etot, p1T);
    k_agg1<<<(N * 64 + 255) / 256, 256, 0, stream>>>(h1bf, p1T, offsets, csr, b1,
                                                     N, Etot, h2in);

    // layer 2
    k_gemm_att<64, 1><<<(N + 63) / 64, 256, 0, stream>>>(h2in, W2, att_s2, att_d2,
                                                         N, h2bf, as2, ad2);
    k_pexp2<<<nb, 256, 0, stream>>>(csr, dloc, bBase, as2, ad2, N, p2);
    k_agg2<<<(N * 64 + 255) / 256, 256, 0, stream>>>(h2bf, p2, offsets, csr, b2,
                                                     N, (float*)d_out);
}

// Round 12
// 148.734 us; speedup vs baseline: 1.4434x; 1.4434x over previous
//
#include <hip/hip_runtime.h>
#include <math.h>

#define IN_CH 128
#define H1N 8
#define C1N 16
#define C2N 64
#define NEG_SLOPE 0.2f

#define BKT_SHIFT 7                 // 128 nodes per bucket
#define BKT_NODES (1 << BKT_SHIFT)
#define NBLK 128                    // blocks for count/bin passes

typedef unsigned short ushortT;

__device__ __forceinline__ ushortT f2bf(float f) {
    unsigned u = __float_as_uint(f);
    unsigned r = u + 0x7FFFu + ((u >> 16) & 1u);
    return (ushortT)(r >> 16);
}
__device__ __forceinline__ float bf2f(ushortT b) {
    return __uint_as_float(((unsigned)b) << 16);
}
__device__ __forceinline__ float leaky(float x) {
    return (x > 0.f) ? x : NEG_SLOPE * x;
}

// ---------------- CSR build: deterministic counting sort, no global atomics ----------------

__global__ __launch_bounds__(512) void k_cnt(const int* __restrict__ src,
                                             const int* __restrict__ dst,
                                             int E, int N, int* __restrict__ cnt) {
    __shared__ int hist[512];
    int blk = blockIdx.x, t = threadIdx.x;
    int nb = (N + BKT_NODES - 1) >> BKT_SHIFT;
    if (t < nb) hist[t] = 0;
    __syncthreads();
    int Etot = E + N;
    int chunk = (Etot + gridDim.x - 1) / gridDim.x;
    int lo = blk * chunk;
    int hi = lo + chunk; if (hi > Etot) hi = Etot;
    for (int i = lo + t; i < hi; i += 512) {
        int d = (i < E) ? dst[i] : (i - E);
        atomicAdd(&hist[d >> BKT_SHIFT], 1);
    }
    __syncthreads();
    if (t < nb) cnt[t * NBLK + blk] = hist[t];
}

__global__ __launch_bounds__(NBLK) void k_scanrel(int* __restrict__ cnt,
                                                  int* __restrict__ bucketTotal) {
    __shared__ int sh[NBLK];
    int b = blockIdx.x, t = threadIdx.x;
    sh[t] = cnt[b * NBLK + t];
    __syncthreads();
    for (int off = 1; off < NBLK; off <<= 1) {
        int v = (t >= off) ? sh[t - off] : 0;
        __syncthreads();
        sh[t] += v;
        __syncthreads();
    }
    if (t == NBLK - 1) bucketTotal[b] = sh[t];
    cnt[b * NBLK + t] = (t == 0) ? 0 : sh[t - 1];
}

__global__ __launch_bounds__(512) void k_scanbucket(const int* __restrict__ bucketTotal,
                                                    int nb, int* __restrict__ bBase,
                                                    int N, int* __restrict__ offsets) {
    __shared__ int sh[512];
    int t = threadIdx.x;
    sh[t] = (t < nb) ? bucketTotal[t] : 0;
    __syncthreads();
    for (int off = 1; off < 512; off <<= 1) {
        int v = (t >= off) ? sh[t - off] : 0;
        __syncthreads();
        sh[t] += v;
        __syncthreads();
    }
    if (t < nb) bBase[t] = (t == 0) ? 0 : sh[t - 1];
    if (t == 511) { bBase[nb] = sh[511]; offsets[N] = sh[511]; }
}

__global__ __launch_bounds__(512) void k_bin(const int* __restrict__ src,
                                             const int* __restrict__ dst,
                                             int E, int N,
                                             const int* __restrict__ cnt,
                                             const int* __restrict__ bBase,
                                             unsigned* __restrict__ pair) {
    __shared__ int cur[512];
    int blk = blockIdx.x, t = threadIdx.x;
    int nb = (N + BKT_NODES - 1) >> BKT_SHIFT;
    if (t < nb) cur[t] = bBase[t] + cnt[t * NBLK + blk];
    __syncthreads();
    int Etot = E + N;
    int chunk = (Etot + gridDim.x - 1) / gridDim.x;
    int lo = blk * chunk;
    int hi = lo + chunk; if (hi > Etot) hi = Etot;
    for (int i = lo + t; i < hi; i += 512) {
        int s, d;
        if (i < E) { s = src[i]; d = dst[i]; }
        else       { s = d = i - E; }
        int b = d >> BKT_SHIFT;
        int pos = atomicAdd(&cur[b], 1);
        pair[pos] = ((unsigned)(d & (BKT_NODES - 1)) << 16) | (unsigned)s;
    }
}

__global__ __launch_bounds__(256) void k_csr_local(const unsigned* __restrict__ pair,
                                                   const int* __restrict__ bBase,
                                                   int N, int* __restrict__ offsets,
                                                   ushortT* __restrict__ csr) {
    __shared__ int hist[BKT_NODES];
    __shared__ int loff[BKT_NODES];
    int b = blockIdx.x;
    int t = threadIdx.x;
    int base = bBase[b];
    int cnt = bBase[b + 1] - base;
    const unsigned* pp = pair + base;

    if (t < BKT_NODES) hist[t] = 0;
    __syncthreads();
    for (int i = t; i < cnt; i += 256) atomicAdd(&hist[pp[i] >> 16], 1);
    __syncthreads();
    if (t < BKT_NODES) loff[t] = hist[t];
    __syncthreads();
    for (int off = 1; off < BKT_NODES; off <<= 1) {
        int v = 0;
        if (t < BKT_NODES && t >= off) v = loff[t - off];
        __syncthreads();
        if (t < BKT_NODES) loff[t] += v;
        __syncthreads();
    }
    int node0 = b << BKT_SHIFT;
    if (t < BKT_NODES) {
        int excl = (t == 0) ? 0 : loff[t - 1];
        hist[t] = excl;
        int g = node0 + t;
        if (g < N) offsets[g] = base + excl;
    }
    __syncthreads();
    for (int i = t; i < cnt; i += 256) {
        unsigned pk = pp[i];
        int pos = atomicAdd(&hist[pk >> 16], 1);
        csr[base + pos] = (ushortT)(pk & 0xFFFFu);
    }
}

// ---------------- GEMM + fused attention coefficients ----------------
// BFIN: A is bf16 (ushort) instead of f32.

template <int KOUT, int HEADS, bool BFIN>
__global__ __launch_bounds__(256) void k_gemm_att(const void* __restrict__ Av,
                                                  const float* __restrict__ W,
                                                  const float* __restrict__ att_s,
                                                  const float* __restrict__ att_d,
                                                  int N, ushortT* __restrict__ Cbf,
                                                  float* __restrict__ as_,
                                                  float* __restrict__ ad_) {
    constexpr int CG  = KOUT / 4;
    constexpr int TY  = 256 / CG;
    constexpr int RPT = 64 / TY;
    constexpr int RW  = (KOUT / HEADS) / 4;
    static_assert(RW == 4 || RW == 16, "reduce width");
    __shared__ float As[64][16];
    __shared__ float Ws[16][KOUT];
    int t = threadIdx.x;
    int row0 = blockIdx.x * 64;
    int tx = t % CG, ty = t / CG;

    float4 acc[RPT];
#pragma unroll
    for (int i = 0; i < RPT; ++i) acc[i] = make_float4(0.f, 0.f, 0.f, 0.f);

    for (int k0 = 0; k0 < IN_CH; k0 += 16) {
        {
            int r  = t >> 2;
            int cc = (t & 3) * 4;
            int gr = row0 + r;
            float4 v = make_float4(0.f, 0.f, 0.f, 0.f);
            if (gr < N) {
                if constexpr (BFIN) {
                    const ushortT* A = (const ushortT*)Av;
                    ushort4 u = *(const ushort4*)(A + (size_t)gr * IN_CH + k0 + cc);
                    v.x = bf2f(u.x); v.y = bf2f(u.y); v.z = bf2f(u.z); v.w = bf2f(u.w);
                } else {
                    const float* A = (const float*)Av;
                    v = *(const float4*)(A + (size_t)gr * IN_CH + k0 + cc);
                }
            }
            *(float4*)(&As[r][cc]) = v;
        }
        {
            constexpr int TOT = 16 * KOUT / 4;
            for (int idx = t; idx < TOT; idx += 256) {
                int rr = idx / (KOUT / 4);
                int cc = (idx % (KOUT / 4)) * 4;
                *(float4*)(&Ws[rr][cc]) = *(const float4*)(W + (size_t)(k0 + rr) * KOUT + cc);
            }
        }
        __syncthreads();
#pragma unroll
        for (int kk = 0; kk < 16; ++kk) {
            float4 w = *(const float4*)(&Ws[kk][tx * 4]);
#pragma unroll
            for (int i = 0; i < RPT; ++i) {
                float a = As[ty * RPT + i][kk];
                acc[i].x += a * w.x; acc[i].y += a * w.y;
                acc[i].z += a * w.z; acc[i].w += a * w.w;
            }
        }
        __syncthreads();
    }

    float4 s4 = *(const float4*)(att_s + tx * 4);
    float4 d4 = *(const float4*)(att_d + tx * 4);
#pragma unroll
    for (int i = 0; i < RPT; ++i) {
        int gr = row0 + ty * RPT + i;
        float as = acc[i].x * s4.x + acc[i].y * s4.y + acc[i].z * s4.z + acc[i].w * s4.w;
        float ad = acc[i].x * d4.x + acc[i].y * d4.y + acc[i].z * d4.z + acc[i].w * d4.w;
#pragma unroll
        for (int o = 1; o < RW; o <<= 1) {
            as += __shfl_xor(as, o);
            ad += __shfl_xor(ad, o);
        }
        if (gr < N) {
            ushort4 pk;
            pk.x = f2bf(acc[i].x); pk.y = f2bf(acc[i].y);
            pk.z = f2bf(acc[i].z); pk.w = f2bf(acc[i].w);
            *(ushort4*)(Cbf + (size_t)gr * KOUT + tx * 4) = pk;
            if ((tx % RW) == 0) {
                int h = tx / RW;
                as_[(size_t)gr * HEADS + h] = as;
                ad_[(size_t)gr * HEADS + h] = ad;
            }
        }
    }
}

// ---------------- layer 1 aggregation (+bias +ELU) ----------------
// R6 structure: one wave per node, producer-shfl exp, unrolled 8-edge batches.
// Output h2in stored as bf16 (halves write traffic + GEMM2 read traffic).

__global__ void k_agg1(const ushortT* __restrict__ h1bf,
                       const float* __restrict__ as1, const float* __restrict__ ad1,
                       const int* __restrict__ offsets, const ushortT* __restrict__ csr,
                       const float* __restrict__ b1,
                       int N, ushortT* __restrict__ h2in) {
    int wid  = (blockIdx.x * blockDim.x + threadIdx.x) >> 6;
    int lane = threadIdx.x & 63;
    if (wid >= N) return;
    int v = wid;
    int hc = lane >> 3;               // consumer head
    int hp = lane & 7;                // producer head
    float adc = ad1[v * H1N + hc];
    float adp = ad1[v * H1N + hp];
    float denom = 0.f, acc0 = 0.f, acc1 = 0.f;
    int beg = offsets[v], end = offsets[v + 1];
    int j = beg;
    for (; j + 8 <= end; j += 8) {
        int ep = lane >> 3;
        int sE = csr[j + ep];
        float a = as1[sE * H1N + hp];
        float pp = __expf(leaky(a + adp));
#pragma unroll
        for (int e = 0; e < 8; ++e) {
            int srcl = e * 8 + hc;
            float pe = __shfl(pp, srcl);
            int   se = __shfl(sE, srcl);
            unsigned q = *(const unsigned*)(h1bf + (size_t)se * IN_CH + lane * 2);
            denom += pe;
            acc0 = fmaf(pe, bf2f((ushortT)(q & 0xFFFFu)), acc0);
            acc1 = fmaf(pe, bf2f((ushortT)(q >> 16)), acc1);
        }
    }
    if (j + 4 <= end) {
        int ep = (lane >> 3) & 3;
        int sE = csr[j + ep];
        float a = as1[sE * H1N + hp];
        float pp = __expf(leaky(a + adp));
#pragma unroll
        for (int e = 0; e < 4; ++e) {
            int srcl = e * 8 + hc;
            float pe = __shfl(pp, srcl);
            int   se = __shfl(sE, srcl);
            unsigned q = *(const unsigned*)(h1bf + (size_t)se * IN_CH + lane * 2);
            denom += pe;
            acc0 = fmaf(pe, bf2f((ushortT)(q & 0xFFFFu)), acc0);
            acc1 = fmaf(pe, bf2f((ushortT)(q >> 16)), acc1);
        }
        j += 4;
    }
    for (; j < end; ++j) {
        int s = csr[j];
        float a = as1[s * H1N + hc];
        unsigned q = *(const unsigned*)(h1bf + (size_t)s * IN_CH + lane * 2);
        float p = __expf(leaky(a + adc));
        denom += p;
        acc0 = fmaf(p, bf2f((ushortT)(q & 0xFFFFu)), acc0);
        acc1 = fmaf(p, bf2f((ushortT)(q >> 16)), acc1);
    }
    float inv = 1.f / (denom + 1e-16f);
    float o0 = acc0 * inv + b1[lane * 2];
    float o1 = acc1 * inv + b1[lane * 2 + 1];
    o0 = (o0 > 0.f) ? o0 : expm1f(o0);
    o1 = (o1 > 0.f) ? o1 : expm1f(o1);
    unsigned pk = ((unsigned)f2bf(o1) << 16) | (unsigned)f2bf(o0);
    *(unsigned*)(h2in + (size_t)v * IN_CH + lane * 2) = pk;
}

// ---------------- layer 2 aggregation (+bias) + log_softmax ----------------
// 2 nodes per wave: 32-lane half owns one node; lane owns channels 2c,2c+1
// (c = lane&31). Both halves run independent unrolled batches -> 16
// outstanding gathers/wave. log_softmax reduces within the half.

__global__ __launch_bounds__(256) void k_agg2(const ushortT* __restrict__ h2bf,
                       const float* __restrict__ as2, const float* __restrict__ ad2,
                       const int* __restrict__ offsets, const ushortT* __restrict__ csr,
                       const float* __restrict__ b2,
                       int N, float* __restrict__ out) {
    int wid  = (blockIdx.x * blockDim.x + threadIdx.x) >> 6;
    int lane = threadIdx.x & 63;
    int half = lane >> 5;
    int v = wid * 2 + half;
    bool alive = (v < N);
    int c2 = (lane & 31) * 2;          // channels c2, c2+1

    float ad = 0.f;
    int beg = 0, end = 0;
    if (alive) {
        ad = ad2[v];
        beg = offsets[v];
        end = offsets[v + 1];
    }
    float denom = 0.f, acc0 = 0.f, acc1 = 0.f;
    int j = beg;
    for (; j + 8 <= end; j += 8) {
        int sE = csr[j + (lane & 7)];
        float p = __expf(leaky(as2[sE] + ad));
#pragma unroll
        for (int e = 0; e < 8; ++e) {
            int srcl = (lane & 32) + e;
            float pe = __shfl(p, srcl);
            int   se = __shfl(sE, srcl);
            unsigned q = *(const unsigned*)(h2bf + (size_t)se * C2N + c2);
            denom += pe;
            acc0 = fmaf(pe, bf2f((ushortT)(q & 0xFFFFu)), acc0);
            acc1 = fmaf(pe, bf2f((ushortT)(q >> 16)), acc1);
        }
    }
    if (j < end) {                     // tail <8
        int m = end - j;
        int ep = lane & 7;
        int sE = 0;
        float p = 0.f;
        if (ep < m) {
            sE = csr[j + ep];
            p = __expf(leaky(as2[sE] + ad));
        }
        for (int e = 0; e < m; ++e) {
            int srcl = (lane & 32) + e;
            float pe = __shfl(p, srcl);
            int   se = __shfl(sE, srcl);
            unsigned q = *(const unsigned*)(h2bf + (size_t)se * C2N + c2);
            denom += pe;
            acc0 = fmaf(pe, bf2f((ushortT)(q & 0xFFFFu)), acc0);
            acc1 = fmaf(pe, bf2f((ushortT)(q >> 16)), acc1);
        }
    }
    float inv = 1.f / (denom + 1e-16f);
    float o0 = acc0 * inv + b2[c2];
    float o1 = acc1 * inv + b2[c2 + 1];
    // log_softmax over the half's 64 channels (32 lanes x 2)
    float mx = fmaxf(o0, o1);
#pragma unroll
    for (int off = 16; off >= 1; off >>= 1) mx = fmaxf(mx, __shfl_xor(mx, off));
    float se2 = __expf(o0 - mx) + __expf(o1 - mx);
#pragma unroll
    for (int off = 16; off >= 1; off >>= 1) se2 += __shfl_xor(se2, off);
    if (alive) {
        float lse = logf(se2);
        float2 ov; ov.x = o0 - mx - lse; ov.y = o1 - mx - lse;
        *(float2*)(out + (size_t)v * C2N + c2) = ov;
    }
}

// ---------------- launch ----------------

extern "C" void kernel_launch(void* const* d_in, const int* in_sizes, int n_in,
                              void* d_out, int out_size, void* d_ws, size_t ws_size,
                              hipStream_t stream) {
    const float* x      = (const float*)d_in[0];
    const int*   ei     = (const int*)d_in[1];
    const float* W1     = (const float*)d_in[2];
    const float* att_s1 = (const float*)d_in[3];
    const float* att_d1 = (const float*)d_in[4];
    const float* b1     = (const float*)d_in[5];
    const float* W2     = (const float*)d_in[6];
    const float* att_s2 = (const float*)d_in[7];
    const float* att_d2 = (const float*)d_in[8];
    const float* b2     = (const float*)d_in[9];

    int N = in_sizes[0] / IN_CH;
    int E = in_sizes[1] / 2;
    const int* srcA = ei;
    const int* dstA = ei + E;
    int Etot = E + N;
    int nb = (N + BKT_NODES - 1) >> BKT_SHIFT;

    char* p = (char*)d_ws;
    auto carve = [&](size_t bytes) {
        void* r = (void*)p;
        p += (bytes + 255) & ~(size_t)255;
        return r;
    };
    ushortT* h1bf = (ushortT*)carve((size_t)N * IN_CH * 2);
    ushortT* h2bf = (ushortT*)carve((size_t)N * C2N * 2);
    ushortT* h2in = (ushortT*)carve((size_t)N * IN_CH * 2);
    float* as1  = (float*)carve((size_t)N * H1N * 4);
    float* ad1  = (float*)carve((size_t)N * H1N * 4);
    float* as2  = (float*)carve((size_t)N * 4);
    float* ad2  = (float*)carve((size_t)N * 4);
    int* offsets     = (int*)carve((size_t)(N + 1) * 4);
    ushortT* csr     = (ushortT*)carve((size_t)(Etot + 16) * 2);  // +pad for tail overread
    int* cnt         = (int*)carve((size_t)nb * NBLK * 4);
    int* bucketTotal = (int*)carve((size_t)nb * 4);
    int* bBase       = (int*)carve((size_t)(nb + 1) * 4);
    unsigned* pair   = (unsigned*)carve((size_t)Etot * 4);

    // CSR build (deterministic counting sort; no global atomics)
    k_cnt<<<NBLK, 512, 0, stream>>>(srcA, dstA, E, N, cnt);
    k_scanrel<<<nb, NBLK, 0, stream>>>(cnt, bucketTotal);
    k_scanbucket<<<1, 512, 0, stream>>>(bucketTotal, nb, bBase, N, offsets);
    k_bin<<<NBLK, 512, 0, stream>>>(srcA, dstA, E, N, cnt, bBase, pair);
    k_csr_local<<<nb, 256, 0, stream>>>(pair, bBase, N, offsets, csr);

    // layer 1
    k_gemm_att<128, 8, false><<<(N + 63) / 64, 256, 0, stream>>>(x, W1, att_s1, att_d1,
                                                                 N, h1bf, as1, ad1);
    k_agg1<<<(N * 64 + 255) / 256, 256, 0, stream>>>(h1bf, as1, ad1, offsets, csr, b1, N, h2in);

    // layer 2
    k_gemm_att<64, 1, true><<<(N + 63) / 64, 256, 0, stream>>>(h2in, W2, att_s2, att_d2,
                                                               N, h2bf, as2, ad2);
    k_agg2<<<(N * 32 + 255) / 256, 256, 0, stream>>>(h2bf, as2, ad2, offsets, csr, b2,
                                                     N, (float*)d_out);
}